// Round 1
// baseline (717.372 us; speedup 1.0000x reference)
//
#include <hip/hip_runtime.h>
#include <math.h>

#define NN 1024
#define BATCH 32
#define GAMMAF 0.01f
#define INV_GAMMA 100.0f
#define GW 0.05f
#define BIGF 1e9f

// One block per batch. Thread i owns row i (tgt index). Anti-diagonal wavefront
// over k = 0..2N-2 with three rotating LDS diagonals. One barrier per diagonal:
// iteration k writes only the buffer holding retired diagonal k-2, which no
// thread reads during iteration k.
__global__ __launch_bounds__(1024) void sdtw_wavefront(const float* __restrict__ inp,
                                                       const float* __restrict__ tgt,
                                                       float* __restrict__ partial) {
    __shared__ float bufA[NN];
    __shared__ float bufB[NN];
    __shared__ float bufC[NN];
    __shared__ float xs[NN];    // inp row for this batch (column values)
    __shared__ float wlut[NN];  // logistic weight as function of |i-j|

    const int b = blockIdx.x;
    const int i = threadIdx.x;

    xs[i] = inp[b * NN + i];
    const float ti = tgt[b * NN + i];

    // w(d) = 1 / (1 + exp(-G * (d - N/2)))
    wlut[i] = 1.0f / (1.0f + __expf(-GW * ((float)i - (float)NN * 0.5f)));

    bufA[i] = BIGF;  // diagonal k-2 (virtual diag -2: all invalid)
    bufB[i] = BIGF;  // diagonal k-1 (virtual diag -1: all invalid)
    __syncthreads();

    float* r2 = bufA;  // diag k-2
    float* r1 = bufB;  // diag k-1
    float* rc = bufC;  // diag k (being written)

    for (int k = 0; k < 2 * NN - 1; ++k) {
        const int j = k - i;
        float r = BIGF;
        if (j >= 0 && j < NN) {
            const float left = r1[i];                       // R(i, j-1)
            const float up   = (i > 0) ? r1[i - 1] : BIGF;  // R(i-1, j)
            float dg         = (i > 0) ? r2[i - 1] : BIGF;  // R(i-1, j-1)
            if (i == 0 && j == 0) dg = 0.0f;                // R(-1,-1) = 0

            int dd = i - j; dd = (dd < 0) ? -dd : dd;
            const float diff = ti - xs[j];
            const float dk = diff * diff * wlut[dd];

            const float m = fminf(dg, fminf(up, left));
            const float s = __expf((m - dg) * INV_GAMMA)
                          + __expf((m - up) * INV_GAMMA)
                          + __expf((m - left) * INV_GAMMA);
            r = dk + m - GAMMAF * __logf(s);
        }
        rc[i] = r;
        __syncthreads();
        float* tmp = r2; r2 = r1; r1 = rc; rc = tmp;
    }

    // After the final rotation, r1 holds diagonal 2N-2; cell (N-1, N-1) is at i = N-1.
    if (i == NN - 1) partial[b] = r1[NN - 1];
}

__global__ __launch_bounds__(64) void reduce_mean32(const float* __restrict__ partial,
                                                    float* __restrict__ out) {
    float v = (threadIdx.x < BATCH) ? partial[threadIdx.x] : 0.0f;
    #pragma unroll
    for (int off = 32; off > 0; off >>= 1) v += __shfl_down(v, off);
    if (threadIdx.x == 0) out[0] = v * (1.0f / (float)BATCH);
}

extern "C" void kernel_launch(void* const* d_in, const int* in_sizes, int n_in,
                              void* d_out, int out_size, void* d_ws, size_t ws_size,
                              hipStream_t stream) {
    const float* inp = (const float*)d_in[0];  // [B, N, 1]
    const float* tgt = (const float*)d_in[1];  // [B, N, 1]
    float* out = (float*)d_out;                // [1]
    float* partial = (float*)d_ws;             // 32 floats scratch

    sdtw_wavefront<<<BATCH, NN, 0, stream>>>(inp, tgt, partial);
    reduce_mean32<<<1, 64, 0, stream>>>(partial, out);
}